// Round 5
// baseline (240.416 us; speedup 1.0000x reference)
//
#include <hip/hip_runtime.h>
#include <hip/hip_bf16.h>

#define BB 32
#define PP 1024
#define HID 512
#define NH 8
#define DD 64
#define MEM 64
#define RANK 64

typedef float f32x4 __attribute__((ext_vector_type(4)));

// Workspace layout (floats)
#define M_OFF   512        // [17][17]
#define G_OFF   18432      // [32][16][1024]

// ---------------------------------------------------------------------------
// Kernel 1 (fused precompute + memsoftmax + tsums + features). Unchanged.
// Blocks 0..255: one (b,h) per block, 1024 threads (16 waves).
// Block 256: M17[i][j] = Σ_r WU[i][r]*WV[j][r] (rank-17 fold matrix).
// ---------------------------------------------------------------------------
__global__ __launch_bounds__(1024) void k_fused(
    const float* __restrict__ x, const float* __restrict__ wq,
    const float* __restrict__ bq, const float* __restrict__ wk,
    const float* __restrict__ wv, const float* __restrict__ bv,
    const float* __restrict__ wmem, const float* __restrict__ wu,
    const float* __restrict__ bu, const float* __restrict__ wv2,
    const float* __restrict__ bv2, float* __restrict__ G,
    float* __restrict__ M17) {
  const int t = threadIdx.x;

  if (blockIdx.x == 256) {
    __shared__ float WU[17 * 64];    // [i][r]
    __shared__ float WVt[64 * 17];   // [r][j]
    const int r = t >> 4;
    const int dq = t & 15;
    for (int j = 0; j < 17; ++j) {
      float su, sv;
      if (j < 16) {
        const int hh = j & 7;
        const float4 w4 = (j < 8) ? *(const float4*)&wv[hh * DD + dq * 4]
                                  : *(const float4*)&bv[hh * DD + dq * 4];
        const float4 u4 = *(const float4*)&wu[r * HID + hh * DD + dq * 4];
        const float4 v4 = *(const float4*)&wv2[r * HID + hh * DD + dq * 4];
        su = u4.x * w4.x + u4.y * w4.y + u4.z * w4.z + u4.w * w4.w;
        sv = v4.x * w4.x + v4.y * w4.y + v4.z * w4.z + v4.w * w4.w;
      } else {
        su = (dq == 0) ? bu[r] : 0.f;
        sv = (dq == 0) ? bv2[r] : 0.f;
      }
      su += __shfl_xor(su, 1); su += __shfl_xor(su, 2);
      su += __shfl_xor(su, 4); su += __shfl_xor(su, 8);
      sv += __shfl_xor(sv, 1); sv += __shfl_xor(sv, 2);
      sv += __shfl_xor(sv, 4); sv += __shfl_xor(sv, 8);
      if (dq == 0) {
        WU[j * 64 + r] = su;
        WVt[r * 17 + j] = sv;
      }
    }
    __syncthreads();
    if (t < 17 * 17) {
      const int ii = t / 17, jj = t - ii * 17;
      float s = 0.f;
      for (int rr = 0; rr < 64; ++rr) s += WU[ii * 64 + rr] * WVt[rr * 17 + jj];
      M17[t] = s;
    }
    return;
  }

  __shared__ float Tl[MEM];
  __shared__ float sS1, sS2;
  const int b = blockIdx.x >> 3;
  const int h = blockIdx.x & 7;
  const int w = t >> 6;      // wave 0..15
  const int lane = t & 63;
  const float* xr = x + b * PP;

  const float xv = xr[t];

  float xs[16];
#pragma unroll
  for (int k = 0; k < 16; ++k) xs[k] = xr[lane + k * 64];

  for (int mi = 0; mi < 4; ++mi) {
    const int m = w * 4 + mi;
    float a = wk[h * DD + lane] * wmem[m * DD + lane];
#pragma unroll
    for (int off = 32; off >= 1; off >>= 1) a += __shfl_xor(a, off);

    float mx = -INFINITY;
#pragma unroll
    for (int k = 0; k < 16; ++k) mx = fmaxf(mx, xs[k] * a);
#pragma unroll
    for (int off = 32; off >= 1; off >>= 1) mx = fmaxf(mx, __shfl_xor(mx, off));

    float s = 0.f, sx = 0.f;
#pragma unroll
    for (int k = 0; k < 16; ++k) {
      const float e = __expf(xs[k] * a - mx);
      s += e;
      sx += e * xs[k];
    }
#pragma unroll
    for (int off = 32; off >= 1; off >>= 1) {
      s += __shfl_xor(s, off);
      sx += __shfl_xor(sx, off);
    }
    if (lane == 0) Tl[m] = sx / s;
  }
  __syncthreads();

  if (t < 64) {
    const float v = Tl[t];
    float s1 = v, s2 = v * v;
#pragma unroll
    for (int off = 32; off >= 1; off >>= 1) {
      s1 += __shfl_xor(s1, off);
      s2 += __shfl_xor(s2, off);
    }
    if (t == 0) { sS1 = s1; sS2 = s2; }
  }
  __syncthreads();

  float a1 = 0.f, a0 = 0.f;
#pragma unroll 8
  for (int d = 0; d < DD; ++d) {
    const float q = xv * wq[h * DD + d] + bq[h * DD + d];
    const float ph = (q > 0.f) ? (q + 1.f) : __expf(q);
    a1 += ph * wv[h * DD + d];
    a0 += ph * bv[h * DD + d];
  }
  const float s1 = sS1, s2 = sS2;
  const float c1 = a1 * s2 + a0 * s1;
  const float c2 = a1 * s1 + a0 * (float)MEM;
  G[(b * 16 + h) * PP + t] = c1;
  G[(b * 16 + 8 + h) * PP + t] = c2;
}

// ---------------------------------------------------------------------------
// Kernel 2: pipelined. Each block owns a 128p x 512q strip of one b:
// folds F once, then 4 q-subtiles with double-buffered Gq. Raw s_barrier +
// lgkmcnt(0)-only wait between subtiles: NT-store burst of subtile k stays
// in flight (counted vmcnt from the ds_write dependency) and drains under
// subtile k+1's compute. 512 blocks = exactly 2 resident per CU.
// ---------------------------------------------------------------------------
__global__ __launch_bounds__(256) void k_coeffs(
    const float* __restrict__ G, const float* __restrict__ M17,
    float* __restrict__ out) {
  __shared__ float Ml[17 * 17];
  __shared__ alignas(16) float Fp[17 * 128];
  __shared__ alignas(16) float Gp[16 * 128];
  __shared__ alignas(16) float Gq[2][16 * 128];
  const int b = blockIdx.z;
  const int p0 = blockIdx.y * 128;
  const int qbase = blockIdx.x * 512;
  const int t = threadIdx.x;
  const float* Gg = G + (size_t)b * 16 * PP;
  const f32x4* Gg4 = (const f32x4*)Gg;

  for (int i = t; i < 17 * 17; i += 256) Ml[i] = M17[i];
  for (int i = t; i < 16 * 128; i += 256) {
    const int row = i >> 7, col = i & 127;
    Gp[i] = Gg[row * PP + p0 + col];
    Gq[0][i] = Gg[row * PP + qbase + col];
  }
  __syncthreads();

  // F-fold (once per block, reused for all 4 q-subtiles)
  for (int i = t; i < 17 * 128; i += 256) {
    const int j = i >> 7, pp = i & 127;
    float f = Ml[16 * 17 + j];
#pragma unroll
    for (int ii = 0; ii < 16; ++ii) f += Gp[ii * 128 + pp] * Ml[ii * 17 + j];
    Fp[i] = f;
  }
  __syncthreads();

  const int pr = t >> 4;          // 0..15 -> p rows pr*8..pr*8+7
  const int qv = t & 15;          // 0..15 -> q cols qv*8..qv*8+7
  const int e0r = t >> 5, ec = t & 31;   // float4 staging slots t, t+256

  for (int qt = 0; qt < 4; ++qt) {
    const int cur = qt & 1, nxt = cur ^ 1;
    const bool more = (qt < 3);
    f32x4 pf0, pf1;
    if (more) {
      const int q4 = (qbase + (qt + 1) * 128) >> 2;
      pf0 = Gg4[e0r * 256 + q4 + ec];            // rows 0..7
      pf1 = Gg4[(e0r + 8) * 256 + q4 + ec];      // rows 8..15
    }

    float acc[8][8];
#pragma unroll
    for (int r = 0; r < 8; ++r) {
      const float f16 = Fp[16 * 128 + pr * 8 + r];
#pragma unroll
      for (int c = 0; c < 8; ++c) acc[r][c] = f16;
    }

#pragma unroll
    for (int j = 0; j < 16; ++j) {
      const float4 fj0 = *(const float4*)&Fp[j * 128 + pr * 8];
      const float4 fj1 = *(const float4*)&Fp[j * 128 + pr * 8 + 4];
      const float4 gj0 = *(const float4*)&Gq[cur][j * 128 + qv * 8];
      const float4 gj1 = *(const float4*)&Gq[cur][j * 128 + qv * 8 + 4];
      const float fr[8] = {fj0.x, fj0.y, fj0.z, fj0.w, fj1.x, fj1.y, fj1.z, fj1.w};
      const float gc[8] = {gj0.x, gj0.y, gj0.z, gj0.w, gj1.x, gj1.y, gj1.z, gj1.w};
#pragma unroll
      for (int r = 0; r < 8; ++r) {
#pragma unroll
        for (int c = 0; c < 8; ++c) acc[r][c] += fr[r] * gc[c];
      }
    }

    const int q0 = qbase + qt * 128;
    const size_t base = ((size_t)b * PP + p0 + pr * 8) * PP + q0 + qv * 8;
#pragma unroll
    for (int r = 0; r < 8; ++r) {
      const f32x4 v0 = {acc[r][0], acc[r][1], acc[r][2], acc[r][3]};
      const f32x4 v1 = {acc[r][4], acc[r][5], acc[r][6], acc[r][7]};
      __builtin_nontemporal_store(v0, (f32x4*)&out[base + (size_t)r * PP]);
      __builtin_nontemporal_store(v1, (f32x4*)&out[base + (size_t)r * PP + 4]);
    }

    if (more) {
      // ds_write depends on pf0/pf1 -> compiler emits a COUNTED vmcnt wait
      // (the 16 NT stores above may remain in flight).
      ((f32x4*)&Gq[nxt][0])[t] = pf0;
      ((f32x4*)&Gq[nxt][0])[t + 256] = pf1;
      asm volatile("s_waitcnt lgkmcnt(0)" ::: "memory");
      __builtin_amdgcn_s_barrier();
      asm volatile("" ::: "memory");
      __builtin_amdgcn_sched_barrier(0);
    }
  }
}

extern "C" void kernel_launch(void* const* d_in, const int* in_sizes, int n_in,
                              void* d_out, int out_size, void* d_ws, size_t ws_size,
                              hipStream_t stream) {
  const float* x    = (const float*)d_in[0];
  const float* wq   = (const float*)d_in[1];
  const float* bq   = (const float*)d_in[2];
  const float* wk   = (const float*)d_in[3];
  const float* bk   = (const float*)d_in[4];  (void)bk;  // drops out of softmax
  const float* wv   = (const float*)d_in[5];
  const float* bv   = (const float*)d_in[6];
  const float* wmem = (const float*)d_in[7];
  const float* wu   = (const float*)d_in[8];
  const float* bu   = (const float*)d_in[9];
  const float* wv2  = (const float*)d_in[10];
  const float* bv2  = (const float*)d_in[11];

  float* ws = (float*)d_ws;
  float* M17 = ws + M_OFF;
  float* G   = ws + G_OFF;
  float* out = (float*)d_out;

  k_fused<<<257, 1024, 0, stream>>>(x, wq, bq, wk, wv, bv, wmem, wu, bu,
                                    wv2, bv2, G, M17);
  k_coeffs<<<dim3(2, 8, 32), 256, 0, stream>>>(G, M17, out);
}

// Round 6
// 196.775 us; speedup vs baseline: 1.2218x; 1.2218x over previous
//
#include <hip/hip_runtime.h>
#include <hip/hip_bf16.h>

#define BB 32
#define PP 1024
#define HID 512
#define NH 8
#define DD 64
#define MEM 64
#define RANK 64

typedef float f32x4 __attribute__((ext_vector_type(4)));

// Workspace layout (floats)
#define M_OFF   512        // [17][17]
#define G_OFF   18432      // [32][16][1024]

// ---------------------------------------------------------------------------
// Kernel 1 (fused precompute + memsoftmax + tsums + features). Unchanged
// from the verified 210.7 µs round-4 version.
// Blocks 0..255: one (b,h) per block, 1024 threads (16 waves).
// Block 256: M17[i][j] = Σ_r WU[i][r]*WV[j][r] (rank-17 fold matrix).
// ---------------------------------------------------------------------------
__global__ __launch_bounds__(1024) void k_fused(
    const float* __restrict__ x, const float* __restrict__ wq,
    const float* __restrict__ bq, const float* __restrict__ wk,
    const float* __restrict__ wv, const float* __restrict__ bv,
    const float* __restrict__ wmem, const float* __restrict__ wu,
    const float* __restrict__ bu, const float* __restrict__ wv2,
    const float* __restrict__ bv2, float* __restrict__ G,
    float* __restrict__ M17) {
  const int t = threadIdx.x;

  if (blockIdx.x == 256) {
    __shared__ float WU[17 * 64];    // [i][r]
    __shared__ float WVt[64 * 17];   // [r][j]
    const int r = t >> 4;
    const int dq = t & 15;
    for (int j = 0; j < 17; ++j) {
      float su, sv;
      if (j < 16) {
        const int hh = j & 7;
        const float4 w4 = (j < 8) ? *(const float4*)&wv[hh * DD + dq * 4]
                                  : *(const float4*)&bv[hh * DD + dq * 4];
        const float4 u4 = *(const float4*)&wu[r * HID + hh * DD + dq * 4];
        const float4 v4 = *(const float4*)&wv2[r * HID + hh * DD + dq * 4];
        su = u4.x * w4.x + u4.y * w4.y + u4.z * w4.z + u4.w * w4.w;
        sv = v4.x * w4.x + v4.y * w4.y + v4.z * w4.z + v4.w * w4.w;
      } else {
        su = (dq == 0) ? bu[r] : 0.f;
        sv = (dq == 0) ? bv2[r] : 0.f;
      }
      su += __shfl_xor(su, 1); su += __shfl_xor(su, 2);
      su += __shfl_xor(su, 4); su += __shfl_xor(su, 8);
      sv += __shfl_xor(sv, 1); sv += __shfl_xor(sv, 2);
      sv += __shfl_xor(sv, 4); sv += __shfl_xor(sv, 8);
      if (dq == 0) {
        WU[j * 64 + r] = su;
        WVt[r * 17 + j] = sv;
      }
    }
    __syncthreads();
    if (t < 17 * 17) {
      const int ii = t / 17, jj = t - ii * 17;
      float s = 0.f;
      for (int rr = 0; rr < 64; ++rr) s += WU[ii * 64 + rr] * WVt[rr * 17 + jj];
      M17[t] = s;
    }
    return;
  }

  __shared__ float Tl[MEM];
  __shared__ float sS1, sS2;
  const int b = blockIdx.x >> 3;
  const int h = blockIdx.x & 7;
  const int w = t >> 6;      // wave 0..15
  const int lane = t & 63;
  const float* xr = x + b * PP;

  const float xv = xr[t];

  float xs[16];
#pragma unroll
  for (int k = 0; k < 16; ++k) xs[k] = xr[lane + k * 64];

  for (int mi = 0; mi < 4; ++mi) {
    const int m = w * 4 + mi;
    float a = wk[h * DD + lane] * wmem[m * DD + lane];
#pragma unroll
    for (int off = 32; off >= 1; off >>= 1) a += __shfl_xor(a, off);

    float mx = -INFINITY;
#pragma unroll
    for (int k = 0; k < 16; ++k) mx = fmaxf(mx, xs[k] * a);
#pragma unroll
    for (int off = 32; off >= 1; off >>= 1) mx = fmaxf(mx, __shfl_xor(mx, off));

    float s = 0.f, sx = 0.f;
#pragma unroll
    for (int k = 0; k < 16; ++k) {
      const float e = __expf(xs[k] * a - mx);
      s += e;
      sx += e * xs[k];
    }
#pragma unroll
    for (int off = 32; off >= 1; off >>= 1) {
      s += __shfl_xor(s, off);
      sx += __shfl_xor(sx, off);
    }
    if (lane == 0) Tl[m] = sx / s;
  }
  __syncthreads();

  if (t < 64) {
    const float v = Tl[t];
    float s1 = v, s2 = v * v;
#pragma unroll
    for (int off = 32; off >= 1; off >>= 1) {
      s1 += __shfl_xor(s1, off);
      s2 += __shfl_xor(s2, off);
    }
    if (t == 0) { sS1 = s1; sS2 = s2; }
  }
  __syncthreads();

  float a1 = 0.f, a0 = 0.f;
#pragma unroll 8
  for (int d = 0; d < DD; ++d) {
    const float q = xv * wq[h * DD + d] + bq[h * DD + d];
    const float ph = (q > 0.f) ? (q + 1.f) : __expf(q);
    a1 += ph * wv[h * DD + d];
    a0 += ph * bv[h * DD + d];
  }
  const float s1 = sS1, s2 = sS2;
  const float c1 = a1 * s2 + a0 * s1;
  const float c2 = a1 * s1 + a0 * (float)MEM;
  G[(b * 16 + h) * PP + t] = c1;
  G[(b * 16 + 8 + h) * PP + t] = c2;
}

// ---------------------------------------------------------------------------
// Kernel 2: REVERTED to round-4 structure (2048 blocks, 128x128 tile, 8x8
// per thread) — launch-level TLP provides store/compute overlap (round-5
// explicit pipeline at 2 blocks/CU was latency-bound, 1.9 TB/s).
// Deltas vs round 4: PLAIN float4 stores (not NT — 134 MB output fits the
// 256 MiB L3; NT forced HBM write floor), float4 staging loads.
// ---------------------------------------------------------------------------
__global__ __launch_bounds__(256) void k_coeffs(
    const float* __restrict__ G, const float* __restrict__ M17,
    float* __restrict__ out) {
  __shared__ float Ml[17 * 17];
  __shared__ alignas(16) float Gp[16 * 128];
  __shared__ alignas(16) float Gq[16 * 128];
  __shared__ alignas(16) float Fl[17 * 128];
  const int b = blockIdx.z;
  const int p0 = blockIdx.y * 128;
  const int q0 = blockIdx.x * 128;
  const int t = threadIdx.x;
  const float* Gg = G + (size_t)b * 16 * PP;
  const f32x4* Gg4 = (const f32x4*)Gg;   // G row stride = PP/4 = 256 float4

  for (int i = t; i < 17 * 17; i += 256) Ml[i] = M17[i];
  // float4 staging: 512 f32x4 slots each, 256 threads -> 2 each
  {
    const int row0 = t >> 5, c0 = t & 31;           // slots [row0][c0]
    ((f32x4*)Gp)[t]       = Gg4[row0 * 256 + (p0 >> 2) + c0];
    ((f32x4*)Gq)[t]       = Gg4[row0 * 256 + (q0 >> 2) + c0];
    ((f32x4*)Gp)[t + 256] = Gg4[(row0 + 8) * 256 + (p0 >> 2) + c0];
    ((f32x4*)Gq)[t + 256] = Gg4[(row0 + 8) * 256 + (q0 >> 2) + c0];
  }
  __syncthreads();

  // Fl[j][pp] = M[16][j] + Σ_i Gp[i][pp]*M[i][j]
  for (int i = t; i < 17 * 128; i += 256) {
    const int j = i >> 7, pp = i & 127;
    float f = Ml[16 * 17 + j];
#pragma unroll
    for (int ii = 0; ii < 16; ++ii) f += Gp[ii * 128 + pp] * Ml[ii * 17 + j];
    Fl[i] = f;
  }
  __syncthreads();

  const int pr = t >> 4;   // 0..15 -> rows pr*8 .. pr*8+7
  const int qv = t & 15;   // 0..15 -> cols qv*8 .. qv*8+7

  float acc[8][8];
#pragma unroll
  for (int r = 0; r < 8; ++r) {
    const float f16 = Fl[16 * 128 + pr * 8 + r];
#pragma unroll
    for (int c = 0; c < 8; ++c) acc[r][c] = f16;
  }

#pragma unroll
  for (int j = 0; j < 16; ++j) {
    const float4 fj0 = *(const float4*)&Fl[j * 128 + pr * 8];
    const float4 fj1 = *(const float4*)&Fl[j * 128 + pr * 8 + 4];
    const float4 gj0 = *(const float4*)&Gq[j * 128 + qv * 8];
    const float4 gj1 = *(const float4*)&Gq[j * 128 + qv * 8 + 4];
    const float fr[8] = {fj0.x, fj0.y, fj0.z, fj0.w, fj1.x, fj1.y, fj1.z, fj1.w};
    const float gc[8] = {gj0.x, gj0.y, gj0.z, gj0.w, gj1.x, gj1.y, gj1.z, gj1.w};
#pragma unroll
    for (int r = 0; r < 8; ++r) {
#pragma unroll
      for (int c = 0; c < 8; ++c) acc[r][c] += fr[r] * gc[c];
    }
  }

  const size_t base = ((size_t)b * PP + p0 + pr * 8) * PP + q0 + qv * 8;
#pragma unroll
  for (int r = 0; r < 8; ++r) {
    const f32x4 v0 = {acc[r][0], acc[r][1], acc[r][2], acc[r][3]};
    const f32x4 v1 = {acc[r][4], acc[r][5], acc[r][6], acc[r][7]};
    *(f32x4*)&out[base + (size_t)r * PP] = v0;
    *(f32x4*)&out[base + (size_t)r * PP + 4] = v1;
  }
}

extern "C" void kernel_launch(void* const* d_in, const int* in_sizes, int n_in,
                              void* d_out, int out_size, void* d_ws, size_t ws_size,
                              hipStream_t stream) {
  const float* x    = (const float*)d_in[0];
  const float* wq   = (const float*)d_in[1];
  const float* bq   = (const float*)d_in[2];
  const float* wk   = (const float*)d_in[3];
  const float* bk   = (const float*)d_in[4];  (void)bk;  // drops out of softmax
  const float* wv   = (const float*)d_in[5];
  const float* bv   = (const float*)d_in[6];
  const float* wmem = (const float*)d_in[7];
  const float* wu   = (const float*)d_in[8];
  const float* bu   = (const float*)d_in[9];
  const float* wv2  = (const float*)d_in[10];
  const float* bv2  = (const float*)d_in[11];

  float* ws = (float*)d_ws;
  float* M17 = ws + M_OFF;
  float* G   = ws + G_OFF;
  float* out = (float*)d_out;

  k_fused<<<257, 1024, 0, stream>>>(x, wq, bq, wk, wv, bv, wmem, wu, bu,
                                    wv2, bv2, G, M17);
  k_coeffs<<<dim3(8, 8, 32), 256, 0, stream>>>(G, M17, out);
}

// Round 7
// 190.061 us; speedup vs baseline: 1.2649x; 1.0353x over previous
//
#include <hip/hip_runtime.h>
#include <hip/hip_bf16.h>

#define BB 32
#define PP 1024
#define HID 512
#define NH 8
#define DD 64
#define MEM 64
#define RANK 64

typedef float f32x4 __attribute__((ext_vector_type(4)));

// Workspace layout (floats)
#define M_OFF   512        // [17][17]
#define G_OFF   18432      // [32][16][1024]

// ---------------------------------------------------------------------------
// Kernel 1 (fused precompute + memsoftmax + tsums + features). Unchanged
// from the verified round-6 version (196.8 µs total).
// Blocks 0..255: one (b,h) per block, 1024 threads (16 waves).
// Block 256: M17[i][j] = Σ_r WU[i][r]*WV[j][r] (rank-17 fold matrix).
// ---------------------------------------------------------------------------
__global__ __launch_bounds__(1024) void k_fused(
    const float* __restrict__ x, const float* __restrict__ wq,
    const float* __restrict__ bq, const float* __restrict__ wk,
    const float* __restrict__ wv, const float* __restrict__ bv,
    const float* __restrict__ wmem, const float* __restrict__ wu,
    const float* __restrict__ bu, const float* __restrict__ wv2,
    const float* __restrict__ bv2, float* __restrict__ G,
    float* __restrict__ M17) {
  const int t = threadIdx.x;

  if (blockIdx.x == 256) {
    __shared__ float WU[17 * 64];    // [i][r]
    __shared__ float WVt[64 * 17];   // [r][j]
    const int r = t >> 4;
    const int dq = t & 15;
    for (int j = 0; j < 17; ++j) {
      float su, sv;
      if (j < 16) {
        const int hh = j & 7;
        const float4 w4 = (j < 8) ? *(const float4*)&wv[hh * DD + dq * 4]
                                  : *(const float4*)&bv[hh * DD + dq * 4];
        const float4 u4 = *(const float4*)&wu[r * HID + hh * DD + dq * 4];
        const float4 v4 = *(const float4*)&wv2[r * HID + hh * DD + dq * 4];
        su = u4.x * w4.x + u4.y * w4.y + u4.z * w4.z + u4.w * w4.w;
        sv = v4.x * w4.x + v4.y * w4.y + v4.z * w4.z + v4.w * w4.w;
      } else {
        su = (dq == 0) ? bu[r] : 0.f;
        sv = (dq == 0) ? bv2[r] : 0.f;
      }
      su += __shfl_xor(su, 1); su += __shfl_xor(su, 2);
      su += __shfl_xor(su, 4); su += __shfl_xor(su, 8);
      sv += __shfl_xor(sv, 1); sv += __shfl_xor(sv, 2);
      sv += __shfl_xor(sv, 4); sv += __shfl_xor(sv, 8);
      if (dq == 0) {
        WU[j * 64 + r] = su;
        WVt[r * 17 + j] = sv;
      }
    }
    __syncthreads();
    if (t < 17 * 17) {
      const int ii = t / 17, jj = t - ii * 17;
      float s = 0.f;
      for (int rr = 0; rr < 64; ++rr) s += WU[ii * 64 + rr] * WVt[rr * 17 + jj];
      M17[t] = s;
    }
    return;
  }

  __shared__ float Tl[MEM];
  __shared__ float sS1, sS2;
  const int b = blockIdx.x >> 3;
  const int h = blockIdx.x & 7;
  const int w = t >> 6;      // wave 0..15
  const int lane = t & 63;
  const float* xr = x + b * PP;

  const float xv = xr[t];

  float xs[16];
#pragma unroll
  for (int k = 0; k < 16; ++k) xs[k] = xr[lane + k * 64];

  for (int mi = 0; mi < 4; ++mi) {
    const int m = w * 4 + mi;
    float a = wk[h * DD + lane] * wmem[m * DD + lane];
#pragma unroll
    for (int off = 32; off >= 1; off >>= 1) a += __shfl_xor(a, off);

    float mx = -INFINITY;
#pragma unroll
    for (int k = 0; k < 16; ++k) mx = fmaxf(mx, xs[k] * a);
#pragma unroll
    for (int off = 32; off >= 1; off >>= 1) mx = fmaxf(mx, __shfl_xor(mx, off));

    float s = 0.f, sx = 0.f;
#pragma unroll
    for (int k = 0; k < 16; ++k) {
      const float e = __expf(xs[k] * a - mx);
      s += e;
      sx += e * xs[k];
    }
#pragma unroll
    for (int off = 32; off >= 1; off >>= 1) {
      s += __shfl_xor(s, off);
      sx += __shfl_xor(sx, off);
    }
    if (lane == 0) Tl[m] = sx / s;
  }
  __syncthreads();

  if (t < 64) {
    const float v = Tl[t];
    float s1 = v, s2 = v * v;
#pragma unroll
    for (int off = 32; off >= 1; off >>= 1) {
      s1 += __shfl_xor(s1, off);
      s2 += __shfl_xor(s2, off);
    }
    if (t == 0) { sS1 = s1; sS2 = s2; }
  }
  __syncthreads();

  float a1 = 0.f, a0 = 0.f;
#pragma unroll 8
  for (int d = 0; d < DD; ++d) {
    const float q = xv * wq[h * DD + d] + bq[h * DD + d];
    const float ph = (q > 0.f) ? (q + 1.f) : __expf(q);
    a1 += ph * wv[h * DD + d];
    a0 += ph * bv[h * DD + d];
  }
  const float s1 = sS1, s2 = sS2;
  const float c1 = a1 * s2 + a0 * s1;
  const float c2 = a1 * s1 + a0 * (float)MEM;
  G[(b * 16 + h) * PP + t] = c1;
  G[(b * 16 + 8 + h) * PP + t] = c2;
}

// ---------------------------------------------------------------------------
// Kernel 2: 2048 blocks, 128x128 tile, plain float4 stores (L3 absorbs the
// 134 MB output — NT regressed, round 6). NEW vs round 6: per-thread 8x8
// tile computed as two sequential 4x8 halves (#pragma unroll 1):
//   (a) live acc halves -> VGPR ~100 -> ~70 -> 6-7 blocks/CU occupancy;
//   (b) half the stores issue mid-kernel -> write drain overlaps the
//       second half's FMA stream instead of bursting at block end.
// LDS reads rise to 1.5 B/FMA — still under the 128 B/cy LDS ceiling, so
// VALU remains the binding pipe.
// ---------------------------------------------------------------------------
__global__ __launch_bounds__(256) void k_coeffs(
    const float* __restrict__ G, const float* __restrict__ M17,
    float* __restrict__ out) {
  __shared__ float Ml[17 * 17];
  __shared__ alignas(16) float Gp[16 * 128];
  __shared__ alignas(16) float Gq[16 * 128];
  __shared__ alignas(16) float Fl[17 * 128];
  const int b = blockIdx.z;
  const int p0 = blockIdx.y * 128;
  const int q0 = blockIdx.x * 128;
  const int t = threadIdx.x;
  const float* Gg = G + (size_t)b * 16 * PP;
  const f32x4* Gg4 = (const f32x4*)Gg;   // G row stride = PP/4 = 256 float4

  for (int i = t; i < 17 * 17; i += 256) Ml[i] = M17[i];
  // float4 staging: 512 f32x4 slots each, 256 threads -> 2 each
  {
    const int row0 = t >> 5, c0 = t & 31;
    ((f32x4*)Gp)[t]       = Gg4[row0 * 256 + (p0 >> 2) + c0];
    ((f32x4*)Gq)[t]       = Gg4[row0 * 256 + (q0 >> 2) + c0];
    ((f32x4*)Gp)[t + 256] = Gg4[(row0 + 8) * 256 + (p0 >> 2) + c0];
    ((f32x4*)Gq)[t + 256] = Gg4[(row0 + 8) * 256 + (q0 >> 2) + c0];
  }
  __syncthreads();

  // Fl[j][pp] = M[16][j] + Σ_i Gp[i][pp]*M[i][j]
  for (int i = t; i < 17 * 128; i += 256) {
    const int j = i >> 7, pp = i & 127;
    float f = Ml[16 * 17 + j];
#pragma unroll
    for (int ii = 0; ii < 16; ++ii) f += Gp[ii * 128 + pp] * Ml[ii * 17 + j];
    Fl[i] = f;
  }
  __syncthreads();

  const int pr = t >> 4;   // 0..15 -> p rows pr*8 .. pr*8+7
  const int qv = t & 15;   // 0..15 -> q cols qv*8 .. qv*8+7

#pragma unroll 1
  for (int half = 0; half < 2; ++half) {
    const int prow = pr * 8 + half * 4;   // 4 p-rows this phase

    float acc[4][8];
#pragma unroll
    for (int r = 0; r < 4; ++r) {
      const float f16 = Fl[16 * 128 + prow + r];
#pragma unroll
      for (int c = 0; c < 8; ++c) acc[r][c] = f16;
    }

#pragma unroll
    for (int j = 0; j < 16; ++j) {
      const float4 fj = *(const float4*)&Fl[j * 128 + prow];
      const float4 gj0 = *(const float4*)&Gq[j * 128 + qv * 8];
      const float4 gj1 = *(const float4*)&Gq[j * 128 + qv * 8 + 4];
      const float fr[4] = {fj.x, fj.y, fj.z, fj.w};
      const float gc[8] = {gj0.x, gj0.y, gj0.z, gj0.w,
                           gj1.x, gj1.y, gj1.z, gj1.w};
#pragma unroll
      for (int r = 0; r < 4; ++r) {
#pragma unroll
        for (int c = 0; c < 8; ++c) acc[r][c] += fr[r] * gc[c];
      }
    }

    const size_t base = ((size_t)b * PP + p0 + prow) * PP + q0 + qv * 8;
#pragma unroll
    for (int r = 0; r < 4; ++r) {
      const f32x4 v0 = {acc[r][0], acc[r][1], acc[r][2], acc[r][3]};
      const f32x4 v1 = {acc[r][4], acc[r][5], acc[r][6], acc[r][7]};
      *(f32x4*)&out[base + (size_t)r * PP] = v0;
      *(f32x4*)&out[base + (size_t)r * PP + 4] = v1;
    }
    // keep phase-A stores ahead of phase-B compute (drain overlap)
    __builtin_amdgcn_sched_barrier(0);
  }
}

extern "C" void kernel_launch(void* const* d_in, const int* in_sizes, int n_in,
                              void* d_out, int out_size, void* d_ws, size_t ws_size,
                              hipStream_t stream) {
  const float* x    = (const float*)d_in[0];
  const float* wq   = (const float*)d_in[1];
  const float* bq   = (const float*)d_in[2];
  const float* wk   = (const float*)d_in[3];
  const float* bk   = (const float*)d_in[4];  (void)bk;  // drops out of softmax
  const float* wv   = (const float*)d_in[5];
  const float* bv   = (const float*)d_in[6];
  const float* wmem = (const float*)d_in[7];
  const float* wu   = (const float*)d_in[8];
  const float* bu   = (const float*)d_in[9];
  const float* wv2  = (const float*)d_in[10];
  const float* bv2  = (const float*)d_in[11];

  float* ws = (float*)d_ws;
  float* M17 = ws + M_OFF;
  float* G   = ws + G_OFF;
  float* out = (float*)d_out;

  k_fused<<<257, 1024, 0, stream>>>(x, wq, bq, wk, wv, bv, wmem, wu, bu,
                                    wv2, bv2, G, M17);
  k_coeffs<<<dim3(8, 8, 32), 256, 0, stream>>>(G, M17, out);
}

// Round 8
// 186.445 us; speedup vs baseline: 1.2895x; 1.0194x over previous
//
#include <hip/hip_runtime.h>
#include <hip/hip_bf16.h>

#define BB 32
#define PP 1024
#define HID 512
#define NH 8
#define DD 64
#define MEM 64
#define RANK 64

typedef float f32x4 __attribute__((ext_vector_type(4)));

// Workspace layout (floats)
#define M_OFF   512        // [17][17]
#define G_OFF   18432      // [32][16][1024]

// ---------------------------------------------------------------------------
// Kernel 1 (fused precompute + memsoftmax + tsums + features). Unchanged
// from the verified round-7 version (190.1 µs total).
// Blocks 0..255: one (b,h) per block, 1024 threads (16 waves).
// Block 256: M17[i][j] = Σ_r WU[i][r]*WV[j][r] (rank-17 fold matrix).
// ---------------------------------------------------------------------------
__global__ __launch_bounds__(1024) void k_fused(
    const float* __restrict__ x, const float* __restrict__ wq,
    const float* __restrict__ bq, const float* __restrict__ wk,
    const float* __restrict__ wv, const float* __restrict__ bv,
    const float* __restrict__ wmem, const float* __restrict__ wu,
    const float* __restrict__ bu, const float* __restrict__ wv2,
    const float* __restrict__ bv2, float* __restrict__ G,
    float* __restrict__ M17) {
  const int t = threadIdx.x;

  if (blockIdx.x == 256) {
    __shared__ float WU[17 * 64];    // [i][r]
    __shared__ float WVt[64 * 17];   // [r][j]
    const int r = t >> 4;
    const int dq = t & 15;
    for (int j = 0; j < 17; ++j) {
      float su, sv;
      if (j < 16) {
        const int hh = j & 7;
        const float4 w4 = (j < 8) ? *(const float4*)&wv[hh * DD + dq * 4]
                                  : *(const float4*)&bv[hh * DD + dq * 4];
        const float4 u4 = *(const float4*)&wu[r * HID + hh * DD + dq * 4];
        const float4 v4 = *(const float4*)&wv2[r * HID + hh * DD + dq * 4];
        su = u4.x * w4.x + u4.y * w4.y + u4.z * w4.z + u4.w * w4.w;
        sv = v4.x * w4.x + v4.y * w4.y + v4.z * w4.z + v4.w * w4.w;
      } else {
        su = (dq == 0) ? bu[r] : 0.f;
        sv = (dq == 0) ? bv2[r] : 0.f;
      }
      su += __shfl_xor(su, 1); su += __shfl_xor(su, 2);
      su += __shfl_xor(su, 4); su += __shfl_xor(su, 8);
      sv += __shfl_xor(sv, 1); sv += __shfl_xor(sv, 2);
      sv += __shfl_xor(sv, 4); sv += __shfl_xor(sv, 8);
      if (dq == 0) {
        WU[j * 64 + r] = su;
        WVt[r * 17 + j] = sv;
      }
    }
    __syncthreads();
    if (t < 17 * 17) {
      const int ii = t / 17, jj = t - ii * 17;
      float s = 0.f;
      for (int rr = 0; rr < 64; ++rr) s += WU[ii * 64 + rr] * WVt[rr * 17 + jj];
      M17[t] = s;
    }
    return;
  }

  __shared__ float Tl[MEM];
  __shared__ float sS1, sS2;
  const int b = blockIdx.x >> 3;
  const int h = blockIdx.x & 7;
  const int w = t >> 6;      // wave 0..15
  const int lane = t & 63;
  const float* xr = x + b * PP;

  const float xv = xr[t];

  float xs[16];
#pragma unroll
  for (int k = 0; k < 16; ++k) xs[k] = xr[lane + k * 64];

  for (int mi = 0; mi < 4; ++mi) {
    const int m = w * 4 + mi;
    float a = wk[h * DD + lane] * wmem[m * DD + lane];
#pragma unroll
    for (int off = 32; off >= 1; off >>= 1) a += __shfl_xor(a, off);

    float mx = -INFINITY;
#pragma unroll
    for (int k = 0; k < 16; ++k) mx = fmaxf(mx, xs[k] * a);
#pragma unroll
    for (int off = 32; off >= 1; off >>= 1) mx = fmaxf(mx, __shfl_xor(mx, off));

    float s = 0.f, sx = 0.f;
#pragma unroll
    for (int k = 0; k < 16; ++k) {
      const float e = __expf(xs[k] * a - mx);
      s += e;
      sx += e * xs[k];
    }
#pragma unroll
    for (int off = 32; off >= 1; off >>= 1) {
      s += __shfl_xor(s, off);
      sx += __shfl_xor(sx, off);
    }
    if (lane == 0) Tl[m] = sx / s;
  }
  __syncthreads();

  if (t < 64) {
    const float v = Tl[t];
    float s1 = v, s2 = v * v;
#pragma unroll
    for (int off = 32; off >= 1; off >>= 1) {
      s1 += __shfl_xor(s1, off);
      s2 += __shfl_xor(s2, off);
    }
    if (t == 0) { sS1 = s1; sS2 = s2; }
  }
  __syncthreads();

  float a1 = 0.f, a0 = 0.f;
#pragma unroll 8
  for (int d = 0; d < DD; ++d) {
    const float q = xv * wq[h * DD + d] + bq[h * DD + d];
    const float ph = (q > 0.f) ? (q + 1.f) : __expf(q);
    a1 += ph * wv[h * DD + d];
    a0 += ph * bv[h * DD + d];
  }
  const float s1 = sS1, s2 = sS2;
  const float c1 = a1 * s2 + a0 * s1;
  const float c2 = a1 * s1 + a0 * (float)MEM;
  G[(b * 16 + h) * PP + t] = c1;
  G[(b * 16 + 8 + h) * PP + t] = c2;
}

// ---------------------------------------------------------------------------
// Kernel 2: 2048 blocks, 128x128 tile, plain float4 stores (L3 absorbs the
// 134 MB output). Round 7 half-split (2 phases of 4x8) confirmed the
// store-drain/occupancy theory (−6.7 µs). This round: QUARTER-split —
// 4 phases of 2x8: live acc 16 regs, VGPR ~55 -> 7-8 blocks/CU, store
// bursts of 8 at 4 interleave points (near-continuous drain overlap).
// ---------------------------------------------------------------------------
__global__ __launch_bounds__(256) void k_coeffs(
    const float* __restrict__ G, const float* __restrict__ M17,
    float* __restrict__ out) {
  __shared__ float Ml[17 * 17];
  __shared__ alignas(16) float Gp[16 * 128];
  __shared__ alignas(16) float Gq[16 * 128];
  __shared__ alignas(16) float Fl[17 * 128];
  const int b = blockIdx.z;
  const int p0 = blockIdx.y * 128;
  const int q0 = blockIdx.x * 128;
  const int t = threadIdx.x;
  const float* Gg = G + (size_t)b * 16 * PP;
  const f32x4* Gg4 = (const f32x4*)Gg;   // G row stride = PP/4 = 256 float4

  for (int i = t; i < 17 * 17; i += 256) Ml[i] = M17[i];
  // float4 staging: 512 f32x4 slots each, 256 threads -> 2 each
  {
    const int row0 = t >> 5, c0 = t & 31;
    ((f32x4*)Gp)[t]       = Gg4[row0 * 256 + (p0 >> 2) + c0];
    ((f32x4*)Gq)[t]       = Gg4[row0 * 256 + (q0 >> 2) + c0];
    ((f32x4*)Gp)[t + 256] = Gg4[(row0 + 8) * 256 + (p0 >> 2) + c0];
    ((f32x4*)Gq)[t + 256] = Gg4[(row0 + 8) * 256 + (q0 >> 2) + c0];
  }
  __syncthreads();

  // Fl[j][pp] = M[16][j] + Σ_i Gp[i][pp]*M[i][j]
  for (int i = t; i < 17 * 128; i += 256) {
    const int j = i >> 7, pp = i & 127;
    float f = Ml[16 * 17 + j];
#pragma unroll
    for (int ii = 0; ii < 16; ++ii) f += Gp[ii * 128 + pp] * Ml[ii * 17 + j];
    Fl[i] = f;
  }
  __syncthreads();

  const int pr = t >> 4;   // 0..15 -> p rows pr*8 .. pr*8+7
  const int qv = t & 15;   // 0..15 -> q cols qv*8 .. qv*8+7

#pragma unroll 1
  for (int ph = 0; ph < 4; ++ph) {
    const int prow = pr * 8 + ph * 2;   // 2 p-rows this phase

    float acc[2][8];
#pragma unroll
    for (int r = 0; r < 2; ++r) {
      const float f16 = Fl[16 * 128 + prow + r];
#pragma unroll
      for (int c = 0; c < 8; ++c) acc[r][c] = f16;
    }

#pragma unroll
    for (int j = 0; j < 16; ++j) {
      const float2 fj = *(const float2*)&Fl[j * 128 + prow];
      const float4 gj0 = *(const float4*)&Gq[j * 128 + qv * 8];
      const float4 gj1 = *(const float4*)&Gq[j * 128 + qv * 8 + 4];
      const float fr[2] = {fj.x, fj.y};
      const float gc[8] = {gj0.x, gj0.y, gj0.z, gj0.w,
                           gj1.x, gj1.y, gj1.z, gj1.w};
#pragma unroll
      for (int r = 0; r < 2; ++r) {
#pragma unroll
        for (int c = 0; c < 8; ++c) acc[r][c] += fr[r] * gc[c];
      }
    }

    const size_t base = ((size_t)b * PP + p0 + prow) * PP + q0 + qv * 8;
#pragma unroll
    for (int r = 0; r < 2; ++r) {
      const f32x4 v0 = {acc[r][0], acc[r][1], acc[r][2], acc[r][3]};
      const f32x4 v1 = {acc[r][4], acc[r][5], acc[r][6], acc[r][7]};
      *(f32x4*)&out[base + (size_t)r * PP] = v0;
      *(f32x4*)&out[base + (size_t)r * PP + 4] = v1;
    }
    // keep this phase's stores ahead of the next phase's compute
    __builtin_amdgcn_sched_barrier(0);
  }
}

extern "C" void kernel_launch(void* const* d_in, const int* in_sizes, int n_in,
                              void* d_out, int out_size, void* d_ws, size_t ws_size,
                              hipStream_t stream) {
  const float* x    = (const float*)d_in[0];
  const float* wq   = (const float*)d_in[1];
  const float* bq   = (const float*)d_in[2];
  const float* wk   = (const float*)d_in[3];
  const float* bk   = (const float*)d_in[4];  (void)bk;  // drops out of softmax
  const float* wv   = (const float*)d_in[5];
  const float* bv   = (const float*)d_in[6];
  const float* wmem = (const float*)d_in[7];
  const float* wu   = (const float*)d_in[8];
  const float* bu   = (const float*)d_in[9];
  const float* wv2  = (const float*)d_in[10];
  const float* bv2  = (const float*)d_in[11];

  float* ws = (float*)d_ws;
  float* M17 = ws + M_OFF;
  float* G   = ws + G_OFF;
  float* out = (float*)d_out;

  k_fused<<<257, 1024, 0, stream>>>(x, wq, bq, wk, wv, bv, wmem, wu, bu,
                                    wv2, bv2, G, M17);
  k_coeffs<<<dim3(8, 8, 32), 256, 0, stream>>>(G, M17, out);
}